// Round 2
// baseline (5202.266 us; speedup 1.0000x reference)
//
#include <hip/hip_runtime.h>

#define NPTS 50000
#define KNB 16
#define FDIM 64
#define OUTC 64
#define FAN 1024   // KNB*FDIM
#define NBL 4      // n values per block

typedef __attribute__((ext_vector_type(4))) float f32x4;
typedef __attribute__((ext_vector_type(8))) short bf16x8;

__device__ __forceinline__ unsigned short f2bf(float f) {
    union { float f; unsigned u; } a; a.f = f;
    return (unsigned short)((a.u + 0x7fffu + ((a.u >> 16) & 1u)) >> 16);
}

// one-time (per launch) conversion of W [64][1024] f32 -> bf16 in d_ws
__global__ void wconv_kernel(const float* __restrict__ W, unsigned short* __restrict__ Wb) {
    int i = blockIdx.x * 256 + threadIdx.x;
    Wb[i] = f2bf(W[i]);
}

template<int USEWB>
__global__ __launch_bounds__(256, 4)
void paiconv_kernel(const float* __restrict__ x, const float* __restrict__ v,
                    const float* __restrict__ aw, const float* __restrict__ W,
                    const unsigned short* __restrict__ Wb,
                    const float* __restrict__ bias, const int* __restrict__ nbr,
                    float* __restrict__ out)
{
    // yel rows padded to 1032 bf16 (2064 B) -> phase-2 row reads hit rotating banks
    __shared__ __align__(16) unsigned short yel[16][1032]; // 33 KB
    __shared__ float adjs[4][256];                         // 4 KB, [k*16+t] per wave
    __shared__ int idxs[4][4][KNB];                        // 1 KB

    const int tid  = threadIdx.x;
    const int w    = tid >> 6;   // wave id = which n of the 4
    const int lane = tid & 63;
    const int n0   = blockIdx.x * NBL;
    const int n    = n0 + w;

    // ---- phase 1 setup: neighbor indices + adj for this wave's n ----
    {   // lane l -> (batch pp, k)
        int pp = lane >> 4, k = lane & 15;
        idxs[w][pp][k] = nbr[(pp * NPTS + n) * KNB + k];
    }

    // adj[n][k][t] = sum_s v[n][s] * adjweight[s][k][t]; 4 entries per lane
    f32x4 v0 = *(const f32x4*)&v[n * 8];
    f32x4 v1 = *(const f32x4*)&v[n * 8 + 4];
    #pragma unroll
    for (int j = 0; j < 4; ++j) {
        int kt = lane + 64 * j;          // kt = k*16 + t
        float a = 0.f;
        #pragma unroll
        for (int s = 0; s < 4; ++s) a += v0[s] * aw[s * 256 + kt];
        #pragma unroll
        for (int s = 0; s < 4; ++s) a += v1[s] * aw[(s + 4) * 256 + kt];
        adjs[w][kt] = a;
    }
    __syncthreads();   // adjs/idxs visible to this wave (same wave wrote, but keep block consistent)

    // ---- phase 1: one (n, pp) pair at a time; y[16] accumulators only ----
    #pragma unroll 1
    for (int pp = 0; pp < 4; ++pp) {
        // neighbor row indices (broadcast LDS reads)
        const float* xb = x + (size_t)pp * NPTS * FDIM + lane;
        float xr[KNB];
        #pragma unroll
        for (int k = 0; k < KNB; ++k) {
            int row = idxs[w][pp][k];
            xr[k] = xb[(size_t)row * FDIM];   // coalesced 256B per wave
        }
        float y[16];
        #pragma unroll
        for (int t = 0; t < 16; ++t) y[t] = 0.f;
        #pragma unroll
        for (int k = 0; k < KNB; ++k) {
            #pragma unroll
            for (int t4 = 0; t4 < 4; ++t4) {
                f32x4 av = *(const f32x4*)&adjs[w][k * 16 + t4 * 4]; // broadcast b128
                #pragma unroll
                for (int tt = 0; tt < 4; ++tt)
                    y[t4 * 4 + tt] += xr[k] * av[tt];
            }
        }
        // elu + store bf16 row p = w*4+pp, col i = t*64 + lane
        int p = w * 4 + pp;
        #pragma unroll
        for (int t = 0; t < 16; ++t) {
            float e = y[t];
            e = e > 0.f ? e : __expf(e) - 1.f;
            yel[p][t * 64 + lane] = f2bf(e);
        }
    }

    __syncthreads();

    // ---- phase 2: wave w owns C-tile rows=16 points, cols c in [16w,16w+16) ----
    // out[p][c] = elu( sum_i yel[p][i] * W[c][i] + b[c] )
    const int cloc = lane & 15;
    const int kg   = lane >> 4;     // k-group 0..3, 8 k's each
    const int c    = w * 16 + cloc;
    f32x4 acc = {0.f, 0.f, 0.f, 0.f};
    #pragma unroll 8
    for (int kt = 0; kt < 32; ++kt) {
        int k0 = kt * 32 + kg * 8;
        // A fragment: lane -> (m = lane&15, k = kg*8 + j) ; same k-map used for B
        bf16x8 afrag = *(const bf16x8*)&yel[cloc][k0];
        bf16x8 bfrag;
        if (USEWB) {
            bfrag = *(const bf16x8*)&Wb[c * FAN + k0];
        } else {
            f32x4 w0 = *(const f32x4*)&W[c * FAN + k0];
            f32x4 w1 = *(const f32x4*)&W[c * FAN + k0 + 4];
            #pragma unroll
            for (int j = 0; j < 4; ++j) {
                bfrag[j]     = (short)f2bf(w0[j]);
                bfrag[j + 4] = (short)f2bf(w1[j]);
            }
        }
        acc = __builtin_amdgcn_mfma_f32_16x16x32_bf16(afrag, bfrag, acc, 0, 0, 0);
    }

    // epilogue: D row = (lane>>4)*4 + reg = local point, col = c
    float bc = bias[c];
    #pragma unroll
    for (int j = 0; j < 4; ++j) {
        int row = kg * 4 + j;
        int nn  = n0 + (row >> 2);
        int pp  = row & 3;
        float val = acc[j] + bc;
        val = val > 0.f ? val : __expf(val) - 1.f;
        if (nn == NPTS - 1) val = 0.f;   // zero_pad: last point zeroed (all b, all c)
        out[(pp * NPTS + nn) * FDIM + c] = val;
    }
}

extern "C" void kernel_launch(void* const* d_in, const int* in_sizes, int n_in,
                              void* d_out, int out_size, void* d_ws, size_t ws_size,
                              hipStream_t stream) {
    const float* x    = (const float*)d_in[0];
    const float* v    = (const float*)d_in[1];
    const float* aw   = (const float*)d_in[2];
    const float* W    = (const float*)d_in[3];
    const float* bias = (const float*)d_in[4];
    const int*   nbr  = (const int*)d_in[5];
    float* out = (float*)d_out;

    dim3 grid(NPTS / NBL), blk(256);
    if (ws_size >= (size_t)(OUTC * FAN * 2)) {
        unsigned short* Wb = (unsigned short*)d_ws;
        wconv_kernel<<<dim3(OUTC * FAN / 256), dim3(256), 0, stream>>>(W, Wb);
        paiconv_kernel<1><<<grid, blk, 0, stream>>>(x, v, aw, W, Wb, bias, nbr, out);
    } else {
        paiconv_kernel<0><<<grid, blk, 0, stream>>>(x, v, aw, W,
                                                    (const unsigned short*)nullptr,
                                                    bias, nbr, out);
    }
}

// Round 4
// 296.670 us; speedup vs baseline: 17.5355x; 17.5355x over previous
//
#include <hip/hip_runtime.h>

#define NPTS 50000
#define KNB 16
#define FDIM 64
#define OUTC 64
#define FAN 1024   // KNB*FDIM
#define NBL 4      // n values per block

typedef __attribute__((ext_vector_type(4))) float f32x4;
typedef __attribute__((ext_vector_type(8))) short bf16x8;
typedef __attribute__((ext_vector_type(4))) short bf16x4;

__device__ __forceinline__ unsigned short f2bf(float f) {
    union { float f; unsigned u; } a; a.f = f;
    return (unsigned short)((a.u + 0x7fffu + ((a.u >> 16) & 1u)) >> 16);
}

// one-time (per launch) conversion of W [64][1024] f32 -> bf16 in d_ws
__global__ void wconv_kernel(const float* __restrict__ W, unsigned short* __restrict__ Wb) {
    int i = blockIdx.x * 256 + threadIdx.x;
    Wb[i] = f2bf(W[i]);
}

template<int USEWB>
__global__ __launch_bounds__(256, 4)
void paiconv_kernel(const float* __restrict__ x, const float* __restrict__ v,
                    const float* __restrict__ aw, const float* __restrict__ W,
                    const unsigned short* __restrict__ Wb,
                    const float* __restrict__ bias, const int* __restrict__ nbr,
                    float* __restrict__ out)
{
    // yel rows padded to 1032 bf16 (2064 B = 129*16): phase-2 b128 reads 2-way banks.
    // Storage is SWIZZLED: logical (t,f) lives at [t*64 + (f ^ ((t&7)<<3))].
    __shared__ __align__(16) unsigned short yel[16][1032]; // 33 KB
    __shared__ int idxs[4][4][KNB];                        // 1 KB

    const int tid  = threadIdx.x;
    const int w    = tid >> 6;   // wave id = which n of the 4
    const int lane = tid & 63;
    const int cl   = lane & 15;
    const int kg   = lane >> 4;  // 16-lane group 0..3
    const int n0   = blockIdx.x * NBL;
    const int n    = n0 + w;

    // neighbor indices for this wave's n: lane l -> (batch pp, k)
    idxs[w][lane >> 4][lane & 15] = nbr[((lane >> 4) * NPTS + n) * KNB + (lane & 15)];

    // ---- B operand for phase-1 MFMA: adj[k][t], K padded to 32 (kg>=2 -> 0) ----
    // adj[k][t] = sum_s v[n][s] * aw[s][k][t];  per lane: k = kg*8+j (j=0..7), t = cl
    f32x4 v0 = *(const f32x4*)&v[n * 8];
    f32x4 v1 = *(const f32x4*)&v[n * 8 + 4];
    float vv[8] = {v0[0], v0[1], v0[2], v0[3], v1[0], v1[1], v1[2], v1[3]};
    bf16x8 badj;
    if (kg < 2) {
        const float* awp = aw + (kg * 8) * KNB + cl;
        #pragma unroll
        for (int j = 0; j < 8; ++j) {
            float a = 0.f;
            #pragma unroll
            for (int s = 0; s < 8; ++s) a += vv[s] * awp[s * 256 + j * KNB];
            badj[j] = (short)f2bf(a);
        }
    } else {
        #pragma unroll
        for (int j = 0; j < 8; ++j) badj[j] = 0;
    }

    // ---- phase 1: per (pp): Y^T = X^T(64x16) * adj(16x16) via 4 MFMA tiles ----
    for (int pp = 0; pp < 4; ++pp) {
        const float* xb = x + (size_t)pp * NPTS * FDIM;
        const int* ip = &idxs[w][pp][(kg & 1) * 8];
        int4 r0 = *(const int4*)ip;          // ds_read_b128 broadcast
        int4 r1 = *(const int4*)(ip + 4);
        const int rows[8] = {r0.x, r0.y, r0.z, r0.w, r1.x, r1.y, r1.z, r1.w};
        const int p = w * 4 + pp;
        #pragma unroll
        for (int ft = 0; ft < 4; ++ft) {
            // A fragment: A[m=cl][k=kg*8+j] = X[k][ft*16+cl] = x[pp, idx[k], ft*16+cl]
            bf16x8 af;
            if (kg < 2) {
                #pragma unroll
                for (int j = 0; j < 8; ++j) {
                    int off = rows[j] * FDIM + ft * 16 + cl;
                    af[j] = (short)f2bf(xb[off]);
                }
            } else {
                #pragma unroll
                for (int j = 0; j < 8; ++j) af[j] = 0;
            }
            f32x4 accv = {0.f, 0.f, 0.f, 0.f};
            accv = __builtin_amdgcn_mfma_f32_16x16x32_bf16(af, badj, accv, 0, 0, 0);
            // D: row(m) = kg*4+r -> f = ft*16+kg*4+r ; col(n) = cl -> t
            const int t  = cl;
            const int fs = (ft * 16 + kg * 4) ^ ((t & 7) << 3);  // swizzled f base
            bf16x4 wv;
            #pragma unroll
            for (int r = 0; r < 4; ++r) {
                float e = accv[r];
                e = e > 0.f ? e : __expf(e) - 1.f;
                wv[r] = (short)f2bf(e);
            }
            *(bf16x4*)&yel[p][t * 64 + fs] = wv;   // ds_write_b64, ~4-way balanced
        }
    }

    __syncthreads();

    // ---- phase 2: wave w owns C-tile rows=16 points, cols c in [16w,16w+16) ----
    const int c = w * 16 + cl;
    f32x4 acc = {0.f, 0.f, 0.f, 0.f};
    #pragma unroll 8
    for (int kt = 0; kt < 32; ++kt) {
        const int t  = kt >> 1;
        const int fs = (((kt & 1) * 32) | (kg * 8)) ^ ((t & 7) << 3);
        bf16x8 afrag = *(const bf16x8*)&yel[cl][t * 64 + fs];   // ds_read_b128
        bf16x8 bfrag;
        const int k0 = kt * 32 + kg * 8;
        if (USEWB) {
            bfrag = *(const bf16x8*)&Wb[c * FAN + k0];
        } else {
            f32x4 w0 = *(const f32x4*)&W[c * FAN + k0];
            f32x4 w1 = *(const f32x4*)&W[c * FAN + k0 + 4];
            #pragma unroll
            for (int j = 0; j < 4; ++j) {
                bfrag[j]     = (short)f2bf(w0[j]);
                bfrag[j + 4] = (short)f2bf(w1[j]);
            }
        }
        acc = __builtin_amdgcn_mfma_f32_16x16x32_bf16(afrag, bfrag, acc, 0, 0, 0);
    }

    // epilogue: D row = kg*4 + r = local point, col = c
    float bc = bias[c];
    #pragma unroll
    for (int j = 0; j < 4; ++j) {
        int row = kg * 4 + j;
        int nn  = n0 + (row >> 2);
        int pp  = row & 3;
        float val = acc[j] + bc;
        val = val > 0.f ? val : __expf(val) - 1.f;
        if (nn == NPTS - 1) val = 0.f;   // zero_pad: last point zeroed (all b, all c)
        out[(pp * NPTS + nn) * FDIM + c] = val;
    }
}

extern "C" void kernel_launch(void* const* d_in, const int* in_sizes, int n_in,
                              void* d_out, int out_size, void* d_ws, size_t ws_size,
                              hipStream_t stream) {
    const float* x    = (const float*)d_in[0];
    const float* v    = (const float*)d_in[1];
    const float* aw   = (const float*)d_in[2];
    const float* W    = (const float*)d_in[3];
    const float* bias = (const float*)d_in[4];
    const int*   nbr  = (const int*)d_in[5];
    float* out = (float*)d_out;

    dim3 grid(NPTS / NBL), blk(256);
    if (ws_size >= (size_t)(OUTC * FAN * 2)) {
        unsigned short* Wb = (unsigned short*)d_ws;
        wconv_kernel<<<dim3(OUTC * FAN / 256), dim3(256), 0, stream>>>(W, Wb);
        paiconv_kernel<1><<<grid, blk, 0, stream>>>(x, v, aw, W, Wb, bias, nbr, out);
    } else {
        paiconv_kernel<0><<<grid, blk, 0, stream>>>(x, v, aw, W,
                                                    (const unsigned short*)nullptr,
                                                    bias, nbr, out);
    }
}

// Round 6
// 227.076 us; speedup vs baseline: 22.9098x; 1.3065x over previous
//
#include <hip/hip_runtime.h>

#define NPTS 50000
#define KNB 16
#define FDIM 64
#define OUTC 64
#define FAN 1024   // KNB*FDIM
#define NBL 4      // n values per block

typedef __attribute__((ext_vector_type(4))) float f32x4;
typedef __attribute__((ext_vector_type(8))) short bf16x8;
typedef __attribute__((ext_vector_type(4))) short bf16x4;

__device__ __forceinline__ unsigned short f2bf(float f) {
    union { float f; unsigned u; } a; a.f = f;
    return (unsigned short)((a.u + 0x7fffu + ((a.u >> 16) & 1u)) >> 16);
}

// one-time (per launch) conversion of W [64][1024] f32 -> bf16 in d_ws
__global__ void wconv_kernel(const float* __restrict__ W, unsigned short* __restrict__ Wb) {
    int i = blockIdx.x * 256 + threadIdx.x;
    Wb[i] = f2bf(W[i]);
}

template<int USEWB>
__global__ __launch_bounds__(256, 4)
void paiconv_kernel(const float* __restrict__ x, const float* __restrict__ v,
                    const float* __restrict__ aw, const float* __restrict__ W,
                    const unsigned short* __restrict__ Wb,
                    const float* __restrict__ bias, const int* __restrict__ nbr,
                    float* __restrict__ out)
{
    // yel rows padded to 1032 bf16 (2064 B): phase-2 b128 reads land on rotating banks.
    // Final storage is SWIZZLED: logical (t,f) lives at [t*64 + (f ^ ((t&7)<<3))].
    // Each row ALSO serves as the phase-1 staging buffer for its own point
    // (subtiled X layout, fully consumed into registers before outputs land).
    __shared__ __align__(16) unsigned short yel[16][1032]; // 33 KB
    __shared__ int idxs[4][4][KNB];                        // 1 KB

    const int tid  = threadIdx.x;
    const int w    = tid >> 6;   // wave id = which n of the 4
    const int lane = tid & 63;
    const int cl   = lane & 15;
    const int kg   = lane >> 4;  // 16-lane group 0..3
    const int n0   = blockIdx.x * NBL;
    const int n    = n0 + w;

    // neighbor indices for this wave's n: lane l -> (batch pp, k)
    idxs[w][lane >> 4][lane & 15] = nbr[((lane >> 4) * NPTS + n) * KNB + (lane & 15)];

    // ---- B operand for phase-1 MFMA: adj[k][t]; k-map k = kg*4+j (j=0..3), j>=4 zero ----
    f32x4 v0 = *(const f32x4*)&v[n * 8];
    f32x4 v1 = *(const f32x4*)&v[n * 8 + 4];
    float vv[8] = {v0[0], v0[1], v0[2], v0[3], v1[0], v1[1], v1[2], v1[3]};
    bf16x8 badj;
    #pragma unroll
    for (int j = 0; j < 4; ++j) {
        float a = 0.f;
        #pragma unroll
        for (int s = 0; s < 8; ++s) a += vv[s] * aw[s * 256 + (kg * 4 + j) * KNB + cl];
        badj[j] = (short)f2bf(a);
    }
    #pragma unroll
    for (int j = 4; j < 8; ++j) badj[j] = 0;

    // staging lane roles: instr i loads row k=i*4+g, f = fq*4..fq*4+3 (coalesced 1KB/instr)
    const int g  = lane >> 4;
    const int fq = lane & 15;

    // prefetch pp=0
    int   rowA0 = idxs[w][0][0 * 4 + g], rowA1 = idxs[w][0][1 * 4 + g],
          rowA2 = idxs[w][0][2 * 4 + g], rowA3 = idxs[w][0][3 * 4 + g];
    f32x4 xA0 = *(const f32x4*)&x[(size_t)rowA0 * FDIM + fq * 4];
    f32x4 xA1 = *(const f32x4*)&x[(size_t)rowA1 * FDIM + fq * 4];
    f32x4 xA2 = *(const f32x4*)&x[(size_t)rowA2 * FDIM + fq * 4];
    f32x4 xA3 = *(const f32x4*)&x[(size_t)rowA3 * FDIM + fq * 4];

    #pragma unroll
    for (int pp = 0; pp < 4; ++pp) {
        // prefetch next pp (issued before any asm barriers of this pp)
        f32x4 xB0, xB1, xB2, xB3;
        if (pp < 3) {
            const float* xb = x + (size_t)(pp + 1) * NPTS * FDIM;
            int rB0 = idxs[w][pp + 1][0 * 4 + g], rB1 = idxs[w][pp + 1][1 * 4 + g],
                rB2 = idxs[w][pp + 1][2 * 4 + g], rB3 = idxs[w][pp + 1][3 * 4 + g];
            xB0 = *(const f32x4*)&xb[(size_t)rB0 * FDIM + fq * 4];
            xB1 = *(const f32x4*)&xb[(size_t)rB1 * FDIM + fq * 4];
            xB2 = *(const f32x4*)&xb[(size_t)rB2 * FDIM + fq * 4];
            xB3 = *(const f32x4*)&xb[(size_t)rB3 * FDIM + fq * 4];
        }

        unsigned short* S = &yel[w * 4 + pp][0];

        // cvt + pack + subtiled store: elem = ft*256 + k*16 + fl, ft=fq>>2, fl=4*(lane&3)
        {
            const int wbase = (fq >> 2) * 256 + 4 * (lane & 3);
            f32x4 xs[4] = {xA0, xA1, xA2, xA3};
            #pragma unroll
            for (int i = 0; i < 4; ++i) {
                bf16x4 pkd;
                #pragma unroll
                for (int d = 0; d < 4; ++d) pkd[d] = (short)f2bf(xs[i][d]);
                *(bf16x4*)&S[wbase + (i * 4 + g) * 16] = pkd;   // ds_write_b64, ~4-way
            }
        }

        // writes visible before transpose-reads (same-wave DS order + belt)
        asm volatile("s_waitcnt lgkmcnt(0)" ::: "memory");
        __builtin_amdgcn_sched_barrier(0);

        // transpose-read fragments (HK pattern): per-lane addr = subtile base + lane*8B;
        // HW delivers lane l elem j = elem[(l&15) + j*16 + (l>>4)*64] of the subtile,
        // i.e. fr_ft[j] = X[kg*4+j][ft*16+cl]. offset: walks the 4 f-subtiles (512B each).
        bf16x4 fr0, fr1, fr2, fr3;
        {
            unsigned ab = (unsigned)(unsigned long long)&S[0] + lane * 8;
            asm volatile("ds_read_b64_tr_b16 %0, %1 offset:0"    : "=v"(fr0) : "v"(ab) : "memory");
            asm volatile("ds_read_b64_tr_b16 %0, %1 offset:512"  : "=v"(fr1) : "v"(ab) : "memory");
            asm volatile("ds_read_b64_tr_b16 %0, %1 offset:1024" : "=v"(fr2) : "v"(ab) : "memory");
            asm volatile("ds_read_b64_tr_b16 %0, %1 offset:1536" : "=v"(fr3) : "v"(ab) : "memory");
        }
        asm volatile("s_waitcnt lgkmcnt(0)" ::: "memory");
        __builtin_amdgcn_sched_barrier(0);

        // 4 MFMAs (K=16 padded to 32 with zero slots) + elu + swizzled output to yel row
        bf16x4 frs[4] = {fr0, fr1, fr2, fr3};
        #pragma unroll
        for (int ft = 0; ft < 4; ++ft) {
            bf16x8 af;
            #pragma unroll
            for (int j = 0; j < 4; ++j) af[j] = frs[ft][j];
            #pragma unroll
            for (int j = 4; j < 8; ++j) af[j] = 0;
            f32x4 accv = {0.f, 0.f, 0.f, 0.f};
            accv = __builtin_amdgcn_mfma_f32_16x16x32_bf16(af, badj, accv, 0, 0, 0);
            // D: row(m) = kg*4+r -> f = ft*16+kg*4+r ; col(n) = cl -> t
            const int t  = cl;
            const int fs = (ft * 16 + kg * 4) ^ ((t & 7) << 3);
            bf16x4 wv;
            #pragma unroll
            for (int r = 0; r < 4; ++r) {
                float e = accv[r];
                e = e > 0.f ? e : __expf(e) - 1.f;
                wv[r] = (short)f2bf(e);
            }
            *(bf16x4*)&S[t * 64 + fs] = wv;   // overwrites staging only after all frs read
        }

        // rotate prefetch buffers
        if (pp < 3) { xA0 = xB0; xA1 = xB1; xA2 = xB2; xA3 = xB3; }
    }

    __syncthreads();

    // ---- phase 2: wave w owns C-tile rows=16 points, cols c in [16w,16w+16) ----
    const int c = w * 16 + cl;
    f32x4 acc = {0.f, 0.f, 0.f, 0.f};
    #pragma unroll 8
    for (int kt = 0; kt < 32; ++kt) {
        const int t  = kt >> 1;
        const int fs = (((kt & 1) * 32) | (kg * 8)) ^ ((t & 7) << 3);
        bf16x8 afrag = *(const bf16x8*)&yel[cl][t * 64 + fs];   // ds_read_b128
        bf16x8 bfrag;
        const int k0 = kt * 32 + kg * 8;
        if (USEWB) {
            bfrag = *(const bf16x8*)&Wb[c * FAN + k0];
        } else {
            f32x4 w0 = *(const f32x4*)&W[c * FAN + k0];
            f32x4 w1 = *(const f32x4*)&W[c * FAN + k0 + 4];
            #pragma unroll
            for (int j = 0; j < 4; ++j) {
                bfrag[j]     = (short)f2bf(w0[j]);
                bfrag[j + 4] = (short)f2bf(w1[j]);
            }
        }
        acc = __builtin_amdgcn_mfma_f32_16x16x32_bf16(afrag, bfrag, acc, 0, 0, 0);
    }

    // epilogue: D row = kg*4 + r = local point, col = c
    float bc = bias[c];
    #pragma unroll
    for (int j = 0; j < 4; ++j) {
        int row = kg * 4 + j;
        int nn  = n0 + (row >> 2);
        int pp  = row & 3;
        float val = acc[j] + bc;
        val = val > 0.f ? val : __expf(val) - 1.f;
        if (nn == NPTS - 1) val = 0.f;   // zero_pad: last point zeroed (all b, all c)
        out[(pp * NPTS + nn) * FDIM + c] = val;
    }
}

extern "C" void kernel_launch(void* const* d_in, const int* in_sizes, int n_in,
                              void* d_out, int out_size, void* d_ws, size_t ws_size,
                              hipStream_t stream) {
    const float* x    = (const float*)d_in[0];
    const float* v    = (const float*)d_in[1];
    const float* aw   = (const float*)d_in[2];
    const float* W    = (const float*)d_in[3];
    const float* bias = (const float*)d_in[4];
    const int*   nbr  = (const int*)d_in[5];
    float* out = (float*)d_out;

    dim3 grid(NPTS / NBL), blk(256);
    if (ws_size >= (size_t)(OUTC * FAN * 2)) {
        unsigned short* Wb = (unsigned short*)d_ws;
        wconv_kernel<<<dim3(OUTC * FAN / 256), dim3(256), 0, stream>>>(W, Wb);
        paiconv_kernel<1><<<grid, blk, 0, stream>>>(x, v, aw, W, Wb, bias, nbr, out);
    } else {
        paiconv_kernel<0><<<grid, blk, 0, stream>>>(x, v, aw, W,
                                                    (const unsigned short*)nullptr,
                                                    bias, nbr, out);
    }
}